// Round 1
// baseline (1863.842 us; speedup 1.0000x reference)
//
#include <hip/hip_runtime.h>
#include <hip/hip_bf16.h>

// PathEmbedding fused kernel for MI355X (gfx950).
//
// Math restructuring (exact, no approximation):
//   att[p,l]   = (h_l wk) . (h_15 wq) = h_l . (Wqk^T ... ) with Wqk[u,i] = sum_v wq[u,v] wk[i,v]
//              = h_l . u_p,   u_p = h_15 @ Wqk
//   context[p] = (sum_l att_l h_l) @ wv
// So key/query/value are never materialized.
//
// GRU per step, per 16-path tile: preacts via mfma_f32_16x16x32_bf16 with
// persistent B-fragments in registers (wave w owns 32 z/r-combined cols +
// 16 xh cols + 16 hh cols -> 24 frags = 96 VGPR/lane).
// Fragment layouts (HW-verified per guide):
//   A[m=lane&15][k=(lane>>4)*8+j], B[k=(lane>>4)*8+j][n=lane&15],
//   C/D[row=(lane>>4)*4+r][col=lane&15]

#define NUM_EDGES 10000
#define NUM_PATHS 30000
#define T_PATHS 16
#define NTILES (NUM_PATHS / T_PATHS) // 1875

typedef float f32x4 __attribute__((ext_vector_type(4)));
typedef short bf16x8 __attribute__((ext_vector_type(8)));

__device__ __forceinline__ short f2bf(float f) {
    union { float f; unsigned u; } v; v.f = f;
    unsigned r = (v.u + 0x7fffu + ((v.u >> 16) & 1u)) >> 16;
    return (short)r;
}
__device__ __forceinline__ float bf2f(short s) {
    union { unsigned u; float f; } v; v.u = ((unsigned)(unsigned short)s) << 16;
    return v.f;
}
__device__ __forceinline__ float fsigmoid(float x) {
    x = fminf(20.f, fmaxf(-20.f, x));
    return 1.0f / (1.0f + __expf(-x));
}
__device__ __forceinline__ float ftanh(float x) {
    x = fminf(15.f, fmaxf(-15.f, x));
    float e = __expf(2.0f * x);
    return (e - 1.0f) / (e + 1.0f);
}

// Wqk[u][i] = sum_v wq[u][v] * wk[i][v]   (128x128, f32, into workspace)
__global__ void wqk_kernel(const float* __restrict__ wq, const float* __restrict__ wk,
                           float* __restrict__ Wqk) {
    int id = blockIdx.x * 256 + threadIdx.x; // 16384 total
    int u = id >> 7, i = id & 127;
    float s = 0.f;
    #pragma unroll 8
    for (int v = 0; v < 128; ++v) s += wq[u * 128 + v] * wk[i * 128 + v];
    Wqk[u * 128 + i] = s;
}

#define MFMA(a, b, c) __builtin_amdgcn_mfma_f32_16x16x32_bf16((a), (b), (c), 0, 0, 0)

__global__ __launch_bounds__(512, 2) void path_emb_kernel(
    const float* __restrict__ inputs, const int* __restrict__ paths,
    const float* __restrict__ Wx, const float* __restrict__ Wr,
    const float* __restrict__ bias_i, const float* __restrict__ bias_r,
    const float* __restrict__ Wqk, const float* __restrict__ wv,
    float* __restrict__ out)
{
    // LDS ~56KB. Inner strides padded (+8 shorts / +4 floats) to rotate banks.
    __shared__ short s_x[16][136];        // x_t staged bf16
    __shared__ short s_h[16][136];        // h bf16 (A-frag source); reused as hi() in epilogue
    __shared__ short s_l[16][136];        // lo() residuals in epilogue
    __shared__ float s_hf[16][132];       // h f32 master
    __shared__ float s_pre[4][16][132];   // planes: z, r, xh, hh; epilogue reuse: 0=u, 1=ctx
    __shared__ float s_bz[128], s_brr[128], s_bxh[128], s_bhh[128];

    const int tid  = threadIdx.x;
    const int w    = tid >> 6;   // wave 0..7
    const int lane = tid & 63;
    const int quad = lane >> 4;
    const int c16  = lane & 15;

    if (tid < 128) {
        s_bz[tid]  = bias_i[tid]       + bias_r[tid];
        s_brr[tid] = bias_i[128 + tid] + bias_r[128 + tid];
        s_bxh[tid] = bias_i[256 + tid];
        s_bhh[tid] = bias_r[256 + tid];
    }

    // ---- persistent B fragments (once per WG) ----
    bf16x8 Bzr[2][8], Bxh[4], Bhh[4];
    #pragma unroll
    for (int nt = 0; nt < 2; ++nt) {
        const int col = 32 * w + 16 * nt + c16;   // 0..255: z then r combined cols
        #pragma unroll
        for (int kc = 0; kc < 8; ++kc) {
            bf16x8 fr;
            #pragma unroll
            for (int j = 0; j < 8; ++j) {
                int k = kc * 32 + quad * 8 + j;   // 0..255 over [x;h]
                float v = (k < 128) ? Wx[k * 384 + col] : Wr[(k - 128) * 384 + col];
                fr[j] = f2bf(v);
            }
            Bzr[nt][kc] = fr;
        }
    }
    {
        const int col = 256 + 16 * w + c16;       // candidate-gate cols
        #pragma unroll
        for (int kc = 0; kc < 4; ++kc) {
            bf16x8 fx, fh;
            #pragma unroll
            for (int j = 0; j < 8; ++j) {
                int k = kc * 32 + quad * 8 + j;
                fx[j] = f2bf(Wx[k * 384 + col]);
                fh[j] = f2bf(Wr[k * 384 + col]);
            }
            Bxh[kc] = fx; Bhh[kc] = fh;
        }
    }

    bf16x8 hist[2][4];  // wave w holds h after steps 2w and 2w+1 (A-frag form)

    for (int tile = blockIdx.x; tile < NTILES; tile += gridDim.x) {
        const int p0 = tile * T_PATHS;
        __syncthreads(); // protect s_h/s_l reuse vs previous tile's epilogue reads

        { // zero h state
            int m = tid >> 5, j = tid & 31;
            *(short4*)&s_h[m][4 * j] = make_short4(0, 0, 0, 0);
            float4 z4; z4.x = z4.y = z4.z = z4.w = 0.f;
            *(float4*)&s_hf[m][4 * j] = z4;
        }

        // ---------------- GRU: 16 steps ----------------
        for (int t = 0; t < 16; ++t) {
            // stage gathered x_t -> bf16 LDS (coalesced 128-wide rows)
            #pragma unroll
            for (int i = 0; i < 4; ++i) {
                int e = tid + 512 * i;
                int p = e >> 7, cc = e & 127;
                int edge = paths[(p0 + p) * 16 + t];
                s_x[p][cc] = f2bf(inputs[edge * 128 + cc]);
            }
            __syncthreads();

            bf16x8 ax[4], ah[4];
            #pragma unroll
            for (int kc = 0; kc < 4; ++kc) {
                ax[kc] = *(const bf16x8*)&s_x[c16][kc * 32 + quad * 8];
                ah[kc] = *(const bf16x8*)&s_h[c16][kc * 32 + quad * 8];
            }
            if (t >= 1 && ((t - 1) >> 1) == w) {   // capture history h_{t-1}
                int i = (t - 1) & 1;
                #pragma unroll
                for (int kc = 0; kc < 4; ++kc) hist[i][kc] = ah[kc];
            }

            f32x4 a0 = {0.f, 0.f, 0.f, 0.f}, a1 = a0, axh = a0, ahh = a0;
            #pragma unroll
            for (int kc = 0; kc < 8; ++kc) {
                bf16x8 av = (kc < 4) ? ax[kc] : ah[kc - 4];
                a0 = MFMA(av, Bzr[0][kc], a0);
                a1 = MFMA(av, Bzr[1][kc], a1);
            }
            #pragma unroll
            for (int kc = 0; kc < 4; ++kc) {
                axh = MFMA(ax[kc], Bxh[kc], axh);
                ahh = MFMA(ah[kc], Bhh[kc], ahh);
            }

            const int plane = (w < 4) ? 0 : 1;
            const int ub = 32 * (w & 3);
            #pragma unroll
            for (int r = 0; r < 4; ++r) {
                int row = quad * 4 + r;
                s_pre[plane][row][ub + c16]      = a0[r];
                s_pre[plane][row][ub + 16 + c16] = a1[r];
                s_pre[2][row][16 * w + c16] = axh[r];
                s_pre[3][row][16 * w + c16] = ahh[r];
            }
            __syncthreads();

            { // gates, f32
                int m = tid >> 5, j = tid & 31, u0 = 4 * j;
                float4 zp = *(const float4*)&s_pre[0][m][u0];
                float4 rp = *(const float4*)&s_pre[1][m][u0];
                float4 xh = *(const float4*)&s_pre[2][m][u0];
                float4 hh = *(const float4*)&s_pre[3][m][u0];
                float4 hp = *(const float4*)&s_hf[m][u0];
                float zpa[4] = {zp.x, zp.y, zp.z, zp.w};
                float rpa[4] = {rp.x, rp.y, rp.z, rp.w};
                float xha[4] = {xh.x, xh.y, xh.z, xh.w};
                float hha[4] = {hh.x, hh.y, hh.z, hh.w};
                float hpa[4] = {hp.x, hp.y, hp.z, hp.w};
                float hn[4];
                #pragma unroll
                for (int q = 0; q < 4; ++q) {
                    int uu = u0 + q;
                    float z = fsigmoid(zpa[q] + s_bz[uu]);
                    float r = fsigmoid(rpa[q] + s_brr[uu]);
                    float cand = ftanh(xha[q] + s_bxh[uu] + r * (hha[q] + s_bhh[uu]));
                    hn[q] = z * hpa[q] + (1.f - z) * cand;
                }
                float4 ho; ho.x = hn[0]; ho.y = hn[1]; ho.z = hn[2]; ho.w = hn[3];
                *(float4*)&s_hf[m][u0] = ho;
                *(short4*)&s_h[m][u0] = make_short4(f2bf(hn[0]), f2bf(hn[1]), f2bf(hn[2]), f2bf(hn[3]));
            }
            __syncthreads();
        }

        // ---------------- epilogue: attention (linear form) ----------------
        { // s_l = lo(h15); zero ctx plane
            int m = tid >> 5, j = tid & 31, u0 = 4 * j;
            #pragma unroll
            for (int q = 0; q < 4; ++q) {
                float hf = s_hf[m][u0 + q];
                short hi = s_h[m][u0 + q];
                s_l[m][u0 + q] = f2bf(hf - bf2f(hi));
                s_pre[1][m][u0 + q] = 0.f;
            }
        }
        __syncthreads();

        { // u = h15 @ Wqk  (split hi/lo bf16, 3 mfma per kc)
            bf16x8 ahi[4], alo[4];
            #pragma unroll
            for (int kc = 0; kc < 4; ++kc) {
                ahi[kc] = *(const bf16x8*)&s_h[c16][kc * 32 + quad * 8];
                alo[kc] = *(const bf16x8*)&s_l[c16][kc * 32 + quad * 8];
            }
            if (w == 7) { // capture h15 as hist[1] of wave 7
                #pragma unroll
                for (int kc = 0; kc < 4; ++kc) hist[1][kc] = ahi[kc];
            }
            f32x4 acc = {0.f, 0.f, 0.f, 0.f};
            #pragma unroll
            for (int kc = 0; kc < 4; ++kc) {
                bf16x8 bhi, blo;
                #pragma unroll
                for (int j = 0; j < 8; ++j) {
                    float v = Wqk[(kc * 32 + quad * 8 + j) * 128 + 16 * w + c16];
                    short h = f2bf(v);
                    bhi[j] = h; blo[j] = f2bf(v - bf2f(h));
                }
                acc = MFMA(ahi[kc], bhi, acc);
                acc = MFMA(ahi[kc], blo, acc);
                acc = MFMA(alo[kc], bhi, acc);
            }
            #pragma unroll
            for (int r = 0; r < 4; ++r)
                s_pre[0][quad * 4 + r][16 * w + c16] = acc[r]; // u, f32
        }
        __syncthreads();

        { // att dots + ctx partial accumulation (wave w covers steps 2w, 2w+1)
            float ctxp[4][8];
            #pragma unroll
            for (int kc = 0; kc < 4; ++kc)
                #pragma unroll
                for (int j = 0; j < 8; ++j) ctxp[kc][j] = 0.f;
            #pragma unroll
            for (int i = 0; i < 2; ++i) {
                float hv[4][8];
                float pd = 0.f;
                #pragma unroll
                for (int kc = 0; kc < 4; ++kc) {
                    #pragma unroll
                    for (int j = 0; j < 8; ++j) {
                        float h = bf2f(hist[i][kc][j]);
                        hv[kc][j] = h;
                        pd += h * s_pre[0][c16][kc * 32 + quad * 8 + j];
                    }
                }
                pd += __shfl_xor(pd, 16);
                pd += __shfl_xor(pd, 32);  // att(m=c16, step=2w+i) on all quads
                #pragma unroll
                for (int kc = 0; kc < 4; ++kc)
                    #pragma unroll
                    for (int j = 0; j < 8; ++j) ctxp[kc][j] += pd * hv[kc][j];
            }
            #pragma unroll
            for (int kc = 0; kc < 4; ++kc)
                #pragma unroll
                for (int j = 0; j < 8; ++j)
                    atomicAdd(&s_pre[1][c16][kc * 32 + quad * 8 + j], ctxp[kc][j]);
        }
        __syncthreads();

        { // split ctx into hi/lo bf16
            int m = tid >> 5, j = tid & 31, u0 = 4 * j;
            #pragma unroll
            for (int q = 0; q < 4; ++q) {
                float v = s_pre[1][m][u0 + q];
                short hi = f2bf(v);
                s_h[m][u0 + q] = hi;
                s_l[m][u0 + q] = f2bf(v - bf2f(hi));
            }
        }
        __syncthreads();

        { // context = ctx @ wv  (split hi/lo), write to global
            bf16x8 ahi[4], alo[4];
            #pragma unroll
            for (int kc = 0; kc < 4; ++kc) {
                ahi[kc] = *(const bf16x8*)&s_h[c16][kc * 32 + quad * 8];
                alo[kc] = *(const bf16x8*)&s_l[c16][kc * 32 + quad * 8];
            }
            f32x4 acc = {0.f, 0.f, 0.f, 0.f};
            #pragma unroll
            for (int kc = 0; kc < 4; ++kc) {
                bf16x8 bhi, blo;
                #pragma unroll
                for (int j = 0; j < 8; ++j) {
                    float v = wv[(kc * 32 + quad * 8 + j) * 128 + 16 * w + c16];
                    short h = f2bf(v);
                    bhi[j] = h; blo[j] = f2bf(v - bf2f(h));
                }
                acc = MFMA(ahi[kc], bhi, acc);
                acc = MFMA(ahi[kc], blo, acc);
                acc = MFMA(alo[kc], bhi, acc);
            }
            #pragma unroll
            for (int r = 0; r < 4; ++r)
                out[(p0 + quad * 4 + r) * 128 + 16 * w + c16] = acc[r];
        }
    }
}

extern "C" void kernel_launch(void* const* d_in, const int* in_sizes, int n_in,
                              void* d_out, int out_size, void* d_ws, size_t ws_size,
                              hipStream_t stream) {
    const float* inputs = (const float*)d_in[0];
    const int*   paths  = (const int*)d_in[1];
    // d_in[2]=idx, d_in[3]=seqs: layout is known (p*16+s), unused
    const float* wx = (const float*)d_in[4];
    const float* wr = (const float*)d_in[5];
    const float* bi = (const float*)d_in[6];
    const float* br = (const float*)d_in[7];
    const float* wq = (const float*)d_in[8];
    const float* wk = (const float*)d_in[9];
    const float* wvp = (const float*)d_in[10];
    float* Wqk = (float*)d_ws;   // 64 KB scratch

    wqk_kernel<<<64, 256, 0, stream>>>(wq, wk, Wqk);
    path_emb_kernel<<<256, 512, 0, stream>>>(inputs, paths, wx, wr, bi, br, Wqk, wvp,
                                             (float*)d_out);
}

// Round 2
// 311.451 us; speedup vs baseline: 5.9844x; 5.9844x over previous
//
#include <hip/hip_runtime.h>
#include <hip/hip_bf16.h>

// PathEmbedding fused kernel for MI355X (gfx950). Round 2.
//
// Math (exact restructure): att[p,l] = h_l . u_p, u_p = h15 @ Wqk,
// Wqk = wq @ wk^T; context = (sum_l att_l h_l) @ wv. No key/query/value.
//
// R2 structure: wave w owns u-slice [16w,16w+16) for ALL gate planes
// (z,r,xh,hh). MFMA C-layout (lane: 8 rows x 1 u-col) == gate layout, so
// gates run in-register in the producing wave; f32 master h in lane regs.
// Only h(bf16) crosses waves, C-scattered into a 16-slot history buffer
// (also serves attention). 2 barriers/step, T=32 paths/tile.
// Fragment layouts (HW-verified): A[m=lane&15][k=quad*8+j],
// B[k=quad*8+j][n=lane&15], C/D[row=quad*4+reg][col=lane&15].

#define NUM_EDGES 10000
#define NUM_PATHS 30000
#define T_PATHS 32
#define NTILES ((NUM_PATHS + T_PATHS - 1) / T_PATHS)  // 938 (last tile ragged: 16 rows)

typedef float f32x4 __attribute__((ext_vector_type(4)));
typedef short bf16x8 __attribute__((ext_vector_type(8)));

__device__ __forceinline__ short f2bf(float f) {
    union { float f; unsigned u; } v; v.f = f;
    unsigned r = (v.u + 0x7fffu + ((v.u >> 16) & 1u)) >> 16;
    return (short)r;
}
__device__ __forceinline__ float bf2f(short s) {
    union { unsigned u; float f; } v; v.u = ((unsigned)(unsigned short)s) << 16;
    return v.f;
}
__device__ __forceinline__ float fsigmoid(float x) {
    x = fminf(20.f, fmaxf(-20.f, x));
    return 1.0f / (1.0f + __expf(-x));
}
__device__ __forceinline__ float ftanh(float x) {
    x = fminf(15.f, fmaxf(-15.f, x));
    float e = __expf(2.0f * x);
    return (e - 1.0f) / (e + 1.0f);
}

// Wqk[u][i] = sum_v wq[u][v] * wk[i][v]   (128x128 f32 into workspace)
__global__ void wqk_kernel(const float* __restrict__ wq, const float* __restrict__ wk,
                           float* __restrict__ Wqk) {
    int id = blockIdx.x * 256 + threadIdx.x;
    int u = id >> 7, i = id & 127;
    float s = 0.f;
    #pragma unroll 8
    for (int v = 0; v < 128; ++v) s += wq[u * 128 + v] * wk[i * 128 + v];
    Wqk[u * 128 + i] = s;
}

#define MFMA(a, b, c) __builtin_amdgcn_mfma_f32_16x16x32_bf16((a), (b), (c), 0, 0, 0)

// hist slot stride: 32 rows * 136 shorts + 8 pad = 4360 shorts = 8720 B
// (2180 words % 32 = 4 -> l-slices land on rotating banks, <=2-way conflicts)
#define HSLOT 4360
#define ROWS 136   // padded row stride in shorts (272 B, 16B-aligned, bank-rotating)

__global__ __launch_bounds__(512, 2) void path_emb_kernel(
    const float* __restrict__ inputs, const int* __restrict__ paths,
    const float* __restrict__ Wx, const float* __restrict__ Wr,
    const float* __restrict__ bias_i, const float* __restrict__ bias_r,
    const float* __restrict__ Wqk, const float* __restrict__ wv,
    float* __restrict__ out)
{
    __shared__ __align__(16) short s_hist[16][HSLOT]; // h_0..h_15 bf16  (139,520 B)
    __shared__ __align__(16) short s_x[T_PATHS * ROWS];   // x_t stage / u-hi / ctx-hi (8704 B)
    __shared__ __align__(16) short s_u2[T_PATHS * ROWS];  // u-lo / ctx-lo            (8704 B)
    __shared__ float s_att[T_PATHS][20];                  // att f32                  (2560 B)
    // total 159,488 B -> 1 WG/CU

    const int tid  = threadIdx.x;
    const int w    = tid >> 6;
    const int lane = tid & 63;
    const int quad = lane >> 4;
    const int c16  = lane & 15;
    const int ucol = 16 * w + c16;        // this lane's gate column
    const int gp   = tid >> 4;            // gather row 0..31
    const int gc   = (tid & 15) * 8;      // gather col chunk

    // per-lane gate biases (scalars)
    const float bz  = bias_i[ucol] + bias_r[ucol];
    const float brr = bias_i[128 + ucol] + bias_r[128 + ucol];
    const float bxh = bias_i[256 + ucol];
    const float bhh = bias_r[256 + ucol];

    // ---- persistent B fragments: all 4 planes for this wave's u-slice ----
    bf16x8 Bz[8], Br[8], Bxh[4], Bhh[4];
    #pragma unroll
    for (int kc = 0; kc < 8; ++kc) {
        bf16x8 fz, fr;
        #pragma unroll
        for (int j = 0; j < 8; ++j) {
            int k = kc * 32 + quad * 8 + j;  // 0..255 over [x;h]
            float vz = (k < 128) ? Wx[k * 384 + ucol] : Wr[(k - 128) * 384 + ucol];
            float vr = (k < 128) ? Wx[k * 384 + 128 + ucol] : Wr[(k - 128) * 384 + 128 + ucol];
            fz[j] = f2bf(vz); fr[j] = f2bf(vr);
        }
        Bz[kc] = fz; Br[kc] = fr;
    }
    #pragma unroll
    for (int kc = 0; kc < 4; ++kc) {
        bf16x8 fx, fh;
        #pragma unroll
        for (int j = 0; j < 8; ++j) {
            int k = kc * 32 + quad * 8 + j;
            fx[j] = f2bf(Wx[k * 384 + 256 + ucol]);
            fh[j] = f2bf(Wr[k * 384 + 256 + ucol]);
        }
        Bxh[kc] = fx; Bhh[kc] = fh;
    }

    for (int tile = blockIdx.x; tile < NTILES; tile += gridDim.x) {
        const int p0 = tile * T_PATHS;
        float hreg[8];                     // f32 master h: rows mt*16+quad*4+r, col ucol
        #pragma unroll
        for (int i = 0; i < 8; ++i) hreg[i] = 0.f;

        // prefetch x_0
        float4 xq0, xq1;
        {
            int pr = min(p0 + gp, NUM_PATHS - 1);
            int e = paths[pr * 16];
            xq0 = *(const float4*)&inputs[e * 128 + gc];
            xq1 = *(const float4*)&inputs[e * 128 + gc + 4];
        }

        // ---------------- GRU: 16 steps, 2 barriers each ----------------
        for (int t = 0; t < 16; ++t) {
            __syncthreads();  // b_pre: prev compute's s_x reads done (also tile fence)
            {   // stage x_t -> LDS (one b128 per thread)
                uint pk0 = (uint)(unsigned short)f2bf(xq0.x) | ((uint)(unsigned short)f2bf(xq0.y) << 16);
                uint pk1 = (uint)(unsigned short)f2bf(xq0.z) | ((uint)(unsigned short)f2bf(xq0.w) << 16);
                uint pk2 = (uint)(unsigned short)f2bf(xq1.x) | ((uint)(unsigned short)f2bf(xq1.y) << 16);
                uint pk3 = (uint)(unsigned short)f2bf(xq1.z) | ((uint)(unsigned short)f2bf(xq1.w) << 16);
                uint4 pk = make_uint4(pk0, pk1, pk2, pk3);
                *(uint4*)&s_x[gp * ROWS + gc] = pk;
            }
            __syncthreads();  // b_mid: x_t (and h_{t-1}) visible

            if (t < 15) {     // prefetch x_{t+1}; completes during compute
                int pr = min(p0 + gp, NUM_PATHS - 1);
                int e = paths[pr * 16 + t + 1];
                xq0 = *(const float4*)&inputs[e * 128 + gc];
                xq1 = *(const float4*)&inputs[e * 128 + gc + 4];
            }

            // A fragments
            bf16x8 ax[2][4], ah[2][4];
            #pragma unroll
            for (int mt = 0; mt < 2; ++mt)
                #pragma unroll
                for (int kc = 0; kc < 4; ++kc)
                    ax[mt][kc] = *(const bf16x8*)&s_x[(mt * 16 + c16) * ROWS + kc * 32 + quad * 8];
            if (t > 0) {
                #pragma unroll
                for (int mt = 0; mt < 2; ++mt)
                    #pragma unroll
                    for (int kc = 0; kc < 4; ++kc)
                        ah[mt][kc] = *(const bf16x8*)&s_hist[t - 1][(mt * 16 + c16) * ROWS + kc * 32 + quad * 8];
            }

            f32x4 az[2], ar[2], acx[2], ach[2];
            #pragma unroll
            for (int mt = 0; mt < 2; ++mt) {
                f32x4 zz = {0.f, 0.f, 0.f, 0.f};
                az[mt] = zz; ar[mt] = zz; acx[mt] = zz; ach[mt] = zz;
            }
            #pragma unroll
            for (int mt = 0; mt < 2; ++mt) {
                #pragma unroll
                for (int kc = 0; kc < 4; ++kc) {
                    az[mt]  = MFMA(ax[mt][kc], Bz[kc],  az[mt]);
                    ar[mt]  = MFMA(ax[mt][kc], Br[kc],  ar[mt]);
                    acx[mt] = MFMA(ax[mt][kc], Bxh[kc], acx[mt]);
                }
            }
            if (t > 0) {
                #pragma unroll
                for (int mt = 0; mt < 2; ++mt) {
                    #pragma unroll
                    for (int kc = 0; kc < 4; ++kc) {
                        az[mt]  = MFMA(ah[mt][kc], Bz[kc + 4], az[mt]);
                        ar[mt]  = MFMA(ah[mt][kc], Br[kc + 4], ar[mt]);
                        ach[mt] = MFMA(ah[mt][kc], Bhh[kc],    ach[mt]);
                    }
                }
            }

            // gates in-register; write h_t bf16 to hist (cross-wave exchange)
            #pragma unroll
            for (int mt = 0; mt < 2; ++mt) {
                #pragma unroll
                for (int r = 0; r < 4; ++r) {
                    int i = mt * 4 + r;
                    float z    = fsigmoid(az[mt][r] + bz);
                    float rr   = fsigmoid(ar[mt][r] + brr);
                    float cand = ftanh(acx[mt][r] + bxh + rr * (ach[mt][r] + bhh));
                    hreg[i] = z * hreg[i] + (1.f - z) * cand;
                    s_hist[t][(mt * 16 + quad * 4 + r) * ROWS + ucol] = f2bf(hreg[i]);
                }
            }
        }

        // ---------------- epilogue ----------------
        __syncthreads();  // b0: step-15 compute done everywhere
        // E0: h15 lo residual -> s_x (C-scatter)
        #pragma unroll
        for (int mt = 0; mt < 2; ++mt)
            #pragma unroll
            for (int r = 0; r < 4; ++r) {
                float hf = hreg[mt * 4 + r];
                short hi = f2bf(hf);
                s_x[(mt * 16 + quad * 4 + r) * ROWS + ucol] = f2bf(hf - bf2f(hi));
            }
        __syncthreads();  // b1

        // E1: u = h15 @ Wqk (hi/lo split, 24 MFMAs)
        f32x4 uacc[2];
        { f32x4 zz = {0.f, 0.f, 0.f, 0.f}; uacc[0] = zz; uacc[1] = zz; }
        #pragma unroll
        for (int kc = 0; kc < 4; ++kc) {
            bf16x8 bhi, blo;
            #pragma unroll
            for (int j = 0; j < 8; ++j) {
                float v = Wqk[(kc * 32 + quad * 8 + j) * 128 + ucol];
                short h = f2bf(v);
                bhi[j] = h; blo[j] = f2bf(v - bf2f(h));
            }
            #pragma unroll
            for (int mt = 0; mt < 2; ++mt) {
                bf16x8 Ahi = *(const bf16x8*)&s_hist[15][(mt * 16 + c16) * ROWS + kc * 32 + quad * 8];
                bf16x8 Alo = *(const bf16x8*)&s_x[(mt * 16 + c16) * ROWS + kc * 32 + quad * 8];
                uacc[mt] = MFMA(Ahi, bhi, uacc[mt]);
                uacc[mt] = MFMA(Ahi, blo, uacc[mt]);
                uacc[mt] = MFMA(Alo, bhi, uacc[mt]);
            }
        }
        __syncthreads();  // b2: s_x (h15-lo) reads done

        // E2: write u hi/lo (C-scatter)
        #pragma unroll
        for (int mt = 0; mt < 2; ++mt)
            #pragma unroll
            for (int r = 0; r < 4; ++r) {
                float v = uacc[mt][r];
                short hi = f2bf(v);
                int off = (mt * 16 + quad * 4 + r) * ROWS + ucol;
                s_x[off] = hi;
                s_u2[off] = f2bf(v - bf2f(hi));
            }
        __syncthreads();  // b3

        // E3: att[p][l] = sum_u u[p][u] * hist_l[p][u]  (thread <-> (p,l))
        {
            int p = tid >> 4, l = tid & 15;
            const short* uh = &s_x[p * ROWS];
            const short* ul = &s_u2[p * ROWS];
            const short* hh = &s_hist[l][p * ROWS];
            float a = 0.f;
            #pragma unroll
            for (int u8 = 0; u8 < 128; u8 += 8) {
                bf16x8 vh = *(const bf16x8*)&uh[u8];
                bf16x8 vl = *(const bf16x8*)&ul[u8];
                bf16x8 vt = *(const bf16x8*)&hh[u8];
                #pragma unroll
                for (int j = 0; j < 8; ++j)
                    a += (bf2f(vh[j]) + bf2f(vl[j])) * bf2f(vt[j]);
            }
            s_att[p][l] = a;
        }
        __syncthreads();  // b4

        // E4: ctx[p][v] = sum_l att[p][l] * hist_l[p][v]; split hi/lo
        {
            int p = tid >> 4, v0 = (tid & 15) * 8;
            float ctx[8];
            #pragma unroll
            for (int j = 0; j < 8; ++j) ctx[j] = 0.f;
            #pragma unroll
            for (int l = 0; l < 16; ++l) {
                float al = s_att[p][l];
                bf16x8 hv = *(const bf16x8*)&s_hist[l][p * ROWS + v0];
                #pragma unroll
                for (int j = 0; j < 8; ++j) ctx[j] += al * bf2f(hv[j]);
            }
            #pragma unroll
            for (int j = 0; j < 8; ++j) {
                short hi = f2bf(ctx[j]);
                s_x[p * ROWS + v0 + j] = hi;
                s_u2[p * ROWS + v0 + j] = f2bf(ctx[j] - bf2f(hi));
            }
        }
        __syncthreads();  // b5

        // E5: out = ctx @ wv (hi/lo split, 24 MFMAs), guarded store
        f32x4 oacc[2];
        { f32x4 zz = {0.f, 0.f, 0.f, 0.f}; oacc[0] = zz; oacc[1] = zz; }
        #pragma unroll
        for (int kc = 0; kc < 4; ++kc) {
            bf16x8 bhi, blo;
            #pragma unroll
            for (int j = 0; j < 8; ++j) {
                float v = wv[(kc * 32 + quad * 8 + j) * 128 + ucol];
                short h = f2bf(v);
                bhi[j] = h; blo[j] = f2bf(v - bf2f(h));
            }
            #pragma unroll
            for (int mt = 0; mt < 2; ++mt) {
                bf16x8 Ahi = *(const bf16x8*)&s_x[(mt * 16 + c16) * ROWS + kc * 32 + quad * 8];
                bf16x8 Alo = *(const bf16x8*)&s_u2[(mt * 16 + c16) * ROWS + kc * 32 + quad * 8];
                oacc[mt] = MFMA(Ahi, bhi, oacc[mt]);
                oacc[mt] = MFMA(Ahi, blo, oacc[mt]);
                oacc[mt] = MFMA(Alo, bhi, oacc[mt]);
            }
        }
        #pragma unroll
        for (int mt = 0; mt < 2; ++mt)
            #pragma unroll
            for (int r = 0; r < 4; ++r) {
                int prow = p0 + mt * 16 + quad * 4 + r;
                if (prow < NUM_PATHS) out[prow * 128 + ucol] = oacc[mt][r];
            }
    }
}

extern "C" void kernel_launch(void* const* d_in, const int* in_sizes, int n_in,
                              void* d_out, int out_size, void* d_ws, size_t ws_size,
                              hipStream_t stream) {
    const float* inputs = (const float*)d_in[0];
    const int*   paths  = (const int*)d_in[1];
    // d_in[2]=idx, d_in[3]=seqs: layout known (p*16+s), unused
    const float* wx  = (const float*)d_in[4];
    const float* wr  = (const float*)d_in[5];
    const float* bi  = (const float*)d_in[6];
    const float* br  = (const float*)d_in[7];
    const float* wq  = (const float*)d_in[8];
    const float* wk  = (const float*)d_in[9];
    const float* wvp = (const float*)d_in[10];
    float* Wqk = (float*)d_ws;

    wqk_kernel<<<64, 256, 0, stream>>>(wq, wk, Wqk);
    path_emb_kernel<<<256, 512, 0, stream>>>(inputs, paths, wx, wr, bi, br, Wqk, wvp,
                                             (float*)d_out);
}